// Round 3
// baseline (145.847 us; speedup 1.0000x reference)
//
#include <hip/hip_runtime.h>
#include <hip/hip_bf16.h>

// B=4, N=512, D=64, H=1. All tensors FLOAT32. Internal math f32.
// Input order: 0 h, 1 x, 2 rij, 3 dij, 4 mask, 5 eW1, 6 eb1, 7 eW2, 8 eb2,
// 9 eW3, 10 eb3, 11 pW1, 12 pb1, 13 pW2, 14 pb2, 15 nW1, 16 nb1, 17 nW2,
// 18 nb2, 19 Wih, 20 bih, 21 Whh, 22 bhh.
// Output: h_new (4*512*64) then x_new (4*512*3), f32, concatenated flat.
//
// Algebraic collapse (H=1): the whole edge/phi/node MLP stack is a scalar
// chain per pair; per-node dots A,C precomputed; m_node@Wih^T collapses to
// S*U+V; gh = h@Whh^T+bhh precomputed per row (LDS-tiled GEMM) so the hot
// kernel's epilogue is fully coalesced.

#define NB 512
#define DB 64
#define ROWS 2048          // B*N
#define H_ELEMS (ROWS * DB)

__device__ __forceinline__ float silu(float x) { return x / (1.0f + __expf(-x)); }
__device__ __forceinline__ float sigmf(float x) { return 1.0f / (1.0f + __expf(-x)); }

// ---------------- Kernel 1: per-node dots, U/V, and gh GEMM ----------------
// blocks 0..63: rows [32b, 32b+32): A,C dots + gh[r,0:192] = h[r]@Whh^T + bhh
// block 64:     U[k] = nW2 . Wih[k,:], V[k] = bih[k] + 512*(nb2 . Wih[k,:])
__global__ __launch_bounds__(256) void egnn_pre(
    const float* __restrict__ h, const float* __restrict__ eW1,
    const float* __restrict__ nW2, const float* __restrict__ nb2,
    const float* __restrict__ Wih, const float* __restrict__ bih,
    const float* __restrict__ Whh, const float* __restrict__ bhh,
    float* __restrict__ A, float* __restrict__ C,
    float* __restrict__ U, float* __restrict__ V,
    float* __restrict__ gh)
{
    const int tid = threadIdx.x;
    if (blockIdx.x < 64) {
        __shared__ float hT[32 * 65];        // +1 pad: conflict-free A/C loop
        __shared__ float WT[64 * 193];       // Whh transposed [d][k], pad 193
        const int rowbase = blockIdx.x * 32;

        for (int idx = tid; idx < 32 * 64; idx += 256) {
            int r = idx >> 6, d = idx & 63;
            hT[r * 65 + d] = h[(size_t)rowbase * 64 + idx];
        }
        for (int idx = tid; idx < 192 * 64; idx += 256) {
            int k = idx >> 6, d = idx & 63;
            WT[d * 193 + k] = Whh[idx];      // coalesced read, stride-193 write
        }
        __syncthreads();

        if (tid < 32) {                       // A, C (conflict-free: stride 65)
            float sa = 0.0f, sc = 0.0f;
            #pragma unroll 8
            for (int d = 0; d < DB; ++d) {
                float hv = hT[tid * 65 + d];
                sa += hv * eW1[d];
                sc += hv * eW1[DB + d];
            }
            A[rowbase + tid] = sa;
            C[rowbase + tid] = sc;
        }

        // gh GEMM: lane <-> k (coalesced / 2-way-free LDS), wave+rg <-> row
        const int lane = tid & 63, wv = tid >> 6;
        float acc[3][8];
        #pragma unroll
        for (int kg = 0; kg < 3; ++kg)
            #pragma unroll
            for (int rg = 0; rg < 8; ++rg) acc[kg][rg] = 0.0f;
        for (int d = 0; d < DB; ++d) {
            float w0 = WT[d * 193 + lane];
            float w1 = WT[d * 193 + 64 + lane];
            float w2 = WT[d * 193 + 128 + lane];
            #pragma unroll
            for (int rg = 0; rg < 8; ++rg) {
                float hv = hT[(wv + 4 * rg) * 65 + d];   // wave-uniform bcast
                acc[0][rg] += hv * w0;
                acc[1][rg] += hv * w1;
                acc[2][rg] += hv * w2;
            }
        }
        #pragma unroll
        for (int kg = 0; kg < 3; ++kg) {
            float bb = bhh[kg * 64 + lane];
            #pragma unroll
            for (int rg = 0; rg < 8; ++rg) {
                int r = wv + 4 * rg;
                gh[(size_t)(rowbase + r) * 192 + kg * 64 + lane] = acc[kg][rg] + bb;
            }
        }
    } else {
        // U/V: lane <-> d (coalesced Wih), butterfly reduce per k
        const int lane = tid & 63, wv = tid >> 6;
        if (wv < 3) {
            float nw  = nW2[lane];
            float nbv = nb2[lane];
            for (int kk = 0; kk < 64; ++kk) {
                int k = wv * 64 + kk;
                float w = Wih[(size_t)k * 64 + lane];
                float su = nw * w, sv = nbv * w;
                #pragma unroll
                for (int off = 32; off > 0; off >>= 1) {
                    su += __shfl_xor(su, off, 64);
                    sv += __shfl_xor(sv, off, 64);
                }
                if (lane == kk) {
                    U[k] = su;
                    V[k] = bih[k] + (float)NB * sv;
                }
            }
        }
    }
}

// ---------------- Kernel 2: pairwise chain + reductions + GRU epilogue ----
__global__ __launch_bounds__(256) void egnn_main(
    const float* __restrict__ h, const float* __restrict__ x,
    const float* __restrict__ rij, const float* __restrict__ dij,
    const float* __restrict__ mask,
    const float* __restrict__ eW1, const float* __restrict__ eb1,
    const float* __restrict__ eW2, const float* __restrict__ eb2,
    const float* __restrict__ eW3, const float* __restrict__ eb3,
    const float* __restrict__ pW1, const float* __restrict__ pb1,
    const float* __restrict__ pW2, const float* __restrict__ pb2,
    const float* __restrict__ nW1, const float* __restrict__ nb1,
    const float* __restrict__ A, const float* __restrict__ C,
    const float* __restrict__ U, const float* __restrict__ V,
    const float* __restrict__ gh,
    float* __restrict__ out)
{
    const int row = blockIdx.x;          // b*N + i
    const int b   = row >> 9;            // N = 512
    const int tid = threadIdx.x;

    const float wd  = eW1[2 * DB];
    const float b1  = eb1[0];
    const float w2  = eW2[0],  b2_ = eb2[0];
    const float w3  = eW3[0],  b3  = eb3[0];
    const float pw1 = pW1[0],  pbi = pb1[0];
    const float pw2 = pW2[0],  pbo = pb2[0];
    const float nw1 = nW1[0],  nbi = nb1[0];

    const float ai = A[row];
    const float mi = mask[row];

    const float2* c2  = (const float2*)(C + (b << 9));
    const float2* mk2 = (const float2*)(mask + (b << 9));
    const float2* dr2 = (const float2*)(dij + (size_t)row * NB);
    const float2* rr2 = (const float2*)(rij + (size_t)row * NB * 3);

    float S = 0.0f, x0 = 0.0f, x1 = 0.0f, x2 = 0.0f;

    {   // thread tid handles j = 2*tid, 2*tid+1 (all vectorized loads)
        float2 cj = c2[tid];
        float2 dv = dr2[tid];
        float2 mj = mk2[tid];
        float2 ra = rr2[3 * tid];
        float2 rb = rr2[3 * tid + 1];
        float2 rc = rr2[3 * tid + 2];

        // j0
        {
            float e1  = ai + cj.x + wd * dv.x + b1;
            float m2  = silu(silu(e1) * w2 + b2_);
            float mij = (m2 * w3 + b3) * (mi * mj.x);
            float phi = silu(mij * pw1 + pbi) * pw2 + pbo;
            S  += silu(mij * nw1 + nbi);
            x0 += ra.x * phi;
            x1 += ra.y * phi;
            x2 += rb.x * phi;
        }
        // j1
        {
            float e1  = ai + cj.y + wd * dv.y + b1;
            float m2  = silu(silu(e1) * w2 + b2_);
            float mij = (m2 * w3 + b3) * (mi * mj.y);
            float phi = silu(mij * pw1 + pbi) * pw2 + pbo;
            S  += silu(mij * nw1 + nbi);
            x0 += rb.y * phi;
            x1 += rc.x * phi;
            x2 += rc.y * phi;
        }
    }

    // ---- block reduction: wave64 shuffle, then cross-wave via LDS ----
    #pragma unroll
    for (int off = 32; off > 0; off >>= 1) {
        S  += __shfl_down(S,  off, 64);
        x0 += __shfl_down(x0, off, 64);
        x1 += __shfl_down(x1, off, 64);
        x2 += __shfl_down(x2, off, 64);
    }
    __shared__ float red[4][4];
    __shared__ float fin[4];
    const int wave = tid >> 6, lane = tid & 63;
    if (lane == 0) {
        red[wave][0] = S; red[wave][1] = x0; red[wave][2] = x1; red[wave][3] = x2;
    }
    __syncthreads();
    if (tid < 4) fin[tid] = red[0][tid] + red[1][tid] + red[2][tid] + red[3][tid];
    __syncthreads();

    // ---- GRU epilogue: fully coalesced (gh precomputed) ----
    if (tid < DB) {
        const int d = tid;
        const float Sf = fin[0];
        const float* ghr_ = gh + (size_t)row * 192;
        float ghr = ghr_[d], ghz = ghr_[DB + d], ghn = ghr_[2 * DB + d];
        float gir = Sf * U[d]          + V[d];
        float giz = Sf * U[DB + d]     + V[DB + d];
        float gin = Sf * U[2 * DB + d] + V[2 * DB + d];
        float r = sigmf(gir + ghr);
        float z = sigmf(giz + ghz);
        float n = tanhf(gin + r * ghn);
        float hv = h[(size_t)row * DB + d];
        out[(size_t)row * DB + d] = ((1.0f - z) * n + z * hv) * mi;
    } else if (tid < DB + 3) {
        const int ci = tid - DB;
        out[H_ELEMS + row * 3 + ci] = x[row * 3 + ci] + fin[1 + ci];
    }
}

extern "C" void kernel_launch(void* const* d_in, const int* in_sizes, int n_in,
                              void* d_out, int out_size, void* d_ws, size_t ws_size,
                              hipStream_t stream) {
    const float* h    = (const float*)d_in[0];
    const float* x    = (const float*)d_in[1];
    const float* rij  = (const float*)d_in[2];
    const float* dij  = (const float*)d_in[3];
    const float* mask = (const float*)d_in[4];
    const float* eW1  = (const float*)d_in[5];
    const float* eb1  = (const float*)d_in[6];
    const float* eW2  = (const float*)d_in[7];
    const float* eb2  = (const float*)d_in[8];
    const float* eW3  = (const float*)d_in[9];
    const float* eb3  = (const float*)d_in[10];
    const float* pW1  = (const float*)d_in[11];
    const float* pb1  = (const float*)d_in[12];
    const float* pW2  = (const float*)d_in[13];
    const float* pb2  = (const float*)d_in[14];
    const float* nW1  = (const float*)d_in[15];
    const float* nb1  = (const float*)d_in[16];
    const float* nW2  = (const float*)d_in[17];
    const float* nb2  = (const float*)d_in[18];
    const float* Wih  = (const float*)d_in[19];
    const float* bih  = (const float*)d_in[20];
    const float* Whh  = (const float*)d_in[21];
    const float* bhh  = (const float*)d_in[22];

    float* A  = (float*)d_ws;           // 2048
    float* C  = A + ROWS;               // 2048
    float* U  = C + ROWS;               // 192
    float* V  = U + 3 * DB;             // 192
    float* gh = V + 3 * DB;             // 2048*192

    egnn_pre<<<65, 256, 0, stream>>>(
        h, eW1, nW2, nb2, Wih, bih, Whh, bhh, A, C, U, V, gh);

    egnn_main<<<ROWS, 256, 0, stream>>>(
        h, x, rij, dij, mask,
        eW1, eb1, eW2, eb2, eW3, eb3,
        pW1, pb1, pW2, pb2, nW1, nb1,
        A, C, U, V, gh,
        (float*)d_out);
}

// Round 4
// 122.328 us; speedup vs baseline: 1.1923x; 1.1923x over previous
//
#include <hip/hip_runtime.h>
#include <hip/hip_bf16.h>

// B=4, N=512, D=64, H=1. All tensors FLOAT32. Internal math f32.
// Input order: 0 h, 1 x, 2 rij, 3 dij, 4 mask, 5 eW1, 6 eb1, 7 eW2, 8 eb2,
// 9 eW3, 10 eb3, 11 pW1, 12 pb1, 13 pW2, 14 pb2, 15 nW1, 16 nb1, 17 nW2,
// 18 nb2, 19 Wih, 20 bih, 21 Whh, 22 bhh.
// Output: h_new (4*512*64) then x_new (4*512*3), f32, concatenated flat.
//
// NOTE (R3 post-mortem): dur_us is dominated by the harness's 0xAA re-poison
// of the ~768 MiB workspace (3 x 256 MiB fills @ ~41 us each = ~123 us at
// 6.3 TB/s, inside the timed window). Kernel structure below is the R2
// version that sat AT that floor (123.9 us); R3's gh-precompute restructure
// exposed +22 us and is reverted. Only retained R3 change: float2-vectorized
// pair loop (validated, instruction-reducing, no ws/structural impact).

#define NB 512
#define DB 64
#define ROWS 2048          // B*N
#define H_ELEMS (ROWS * DB)

__device__ __forceinline__ float silu(float x) { return x / (1.0f + __expf(-x)); }
__device__ __forceinline__ float sigmf(float x) { return 1.0f / (1.0f + __expf(-x)); }

// ---------------- Kernel 1: per-node dots + GRU input-collapse vectors ----
// A[row] = h[row,:] . eW1[0:64,0]
// C[row] = h[row,:] . eW1[64:128,0]
// U[k]   = nW2[0,:] . Wih[k,:]            (k in [0,192))
// V[k]   = bih[k] + N * (nb2 . Wih[k,:])
__global__ __launch_bounds__(256) void egnn_pre(
    const float* __restrict__ h, const float* __restrict__ eW1,
    const float* __restrict__ nW2, const float* __restrict__ nb2,
    const float* __restrict__ Wih, const float* __restrict__ bih,
    float* __restrict__ A, float* __restrict__ C,
    float* __restrict__ U, float* __restrict__ V)
{
    int t = blockIdx.x * blockDim.x + threadIdx.x;
    if (t < ROWS) {
        const float* hr = h + (size_t)t * DB;
        float sa = 0.0f, sc = 0.0f;
        #pragma unroll 8
        for (int d = 0; d < DB; ++d) {
            float hv = hr[d];
            sa += hv * eW1[d];
            sc += hv * eW1[DB + d];
        }
        A[t] = sa; C[t] = sc;
    } else if (t < ROWS + 3 * DB) {
        int k = t - ROWS;
        const float* wr = Wih + (size_t)k * DB;
        float su = 0.0f, sv = 0.0f;
        #pragma unroll 8
        for (int d = 0; d < DB; ++d) {
            float w = wr[d];
            su += nW2[d] * w;
            sv += nb2[d] * w;
        }
        U[k] = su;
        V[k] = bih[k] + (float)NB * sv;
    }
}

// ---------------- Kernel 2: pairwise chain + reductions + GRU epilogue ----
__global__ __launch_bounds__(256) void egnn_main(
    const float* __restrict__ h, const float* __restrict__ x,
    const float* __restrict__ rij, const float* __restrict__ dij,
    const float* __restrict__ mask,
    const float* __restrict__ eW1, const float* __restrict__ eb1,
    const float* __restrict__ eW2, const float* __restrict__ eb2,
    const float* __restrict__ eW3, const float* __restrict__ eb3,
    const float* __restrict__ pW1, const float* __restrict__ pb1,
    const float* __restrict__ pW2, const float* __restrict__ pb2,
    const float* __restrict__ nW1, const float* __restrict__ nb1,
    const float* __restrict__ Whh, const float* __restrict__ bhh,
    const float* __restrict__ A, const float* __restrict__ C,
    const float* __restrict__ U, const float* __restrict__ V,
    float* __restrict__ out)
{
    const int row = blockIdx.x;          // b*N + i
    const int b   = row >> 9;            // N = 512
    const int tid = threadIdx.x;

    const float wd  = eW1[2 * DB];
    const float b1  = eb1[0];
    const float w2  = eW2[0],  b2_ = eb2[0];
    const float w3  = eW3[0],  b3  = eb3[0];
    const float pw1 = pW1[0],  pbi = pb1[0];
    const float pw2 = pW2[0],  pbo = pb2[0];
    const float nw1 = nW1[0],  nbi = nb1[0];

    const float ai = A[row];
    const float mi = mask[row];

    const float2* c2  = (const float2*)(C + (b << 9));
    const float2* mk2 = (const float2*)(mask + (b << 9));
    const float2* dr2 = (const float2*)(dij + (size_t)row * NB);
    const float2* rr2 = (const float2*)(rij + (size_t)row * NB * 3);

    float S = 0.0f, x0 = 0.0f, x1 = 0.0f, x2 = 0.0f;

    {   // thread tid handles j = 2*tid, 2*tid+1 (all vectorized loads)
        float2 cj = c2[tid];
        float2 dv = dr2[tid];
        float2 mj = mk2[tid];
        float2 ra = rr2[3 * tid];
        float2 rb = rr2[3 * tid + 1];
        float2 rc = rr2[3 * tid + 2];

        // j0
        {
            float e1  = ai + cj.x + wd * dv.x + b1;
            float m2  = silu(silu(e1) * w2 + b2_);
            float mij = (m2 * w3 + b3) * (mi * mj.x);
            float phi = silu(mij * pw1 + pbi) * pw2 + pbo;
            S  += silu(mij * nw1 + nbi);
            x0 += ra.x * phi;
            x1 += ra.y * phi;
            x2 += rb.x * phi;
        }
        // j1
        {
            float e1  = ai + cj.y + wd * dv.y + b1;
            float m2  = silu(silu(e1) * w2 + b2_);
            float mij = (m2 * w3 + b3) * (mi * mj.y);
            float phi = silu(mij * pw1 + pbi) * pw2 + pbo;
            S  += silu(mij * nw1 + nbi);
            x0 += rb.y * phi;
            x1 += rc.x * phi;
            x2 += rc.y * phi;
        }
    }

    // ---- block reduction: wave64 shuffle, then cross-wave via LDS ----
    #pragma unroll
    for (int off = 32; off > 0; off >>= 1) {
        S  += __shfl_down(S,  off, 64);
        x0 += __shfl_down(x0, off, 64);
        x1 += __shfl_down(x1, off, 64);
        x2 += __shfl_down(x2, off, 64);
    }
    __shared__ float red[4][4];
    __shared__ float fin[4];
    __shared__ float hrow[DB];
    const int wave = tid >> 6, lane = tid & 63;
    if (lane == 0) {
        red[wave][0] = S; red[wave][1] = x0; red[wave][2] = x1; red[wave][3] = x2;
    }
    if (tid < DB) hrow[tid] = h[(size_t)row * DB + tid];
    __syncthreads();
    if (tid < 4) fin[tid] = red[0][tid] + red[1][tid] + red[2][tid] + red[3][tid];
    __syncthreads();

    // ---- GRU epilogue: lanes 0..63 each produce one output channel ----
    if (tid < DB) {
        const float Sf = fin[0];
        const int d = tid;
        const float* Wr = Whh + (size_t)d * DB;
        const float* Wz = Whh + (size_t)(DB + d) * DB;
        const float* Wn = Whh + (size_t)(2 * DB + d) * DB;
        float ghr = bhh[d];
        float ghz = bhh[DB + d];
        float ghn = bhh[2 * DB + d];
        #pragma unroll 8
        for (int k = 0; k < DB; ++k) {
            float hv = hrow[k];
            ghr += hv * Wr[k];
            ghz += hv * Wz[k];
            ghn += hv * Wn[k];
        }
        float gir = Sf * U[d]          + V[d];
        float giz = Sf * U[DB + d]     + V[DB + d];
        float gin = Sf * U[2 * DB + d] + V[2 * DB + d];
        float r = sigmf(gir + ghr);
        float z = sigmf(giz + ghz);
        float n = tanhf(gin + r * ghn);
        float hn = (1.0f - z) * n + z * hrow[d];
        hn *= mi;
        out[(size_t)row * DB + d] = hn;
    } else if (tid < DB + 3) {
        const int ci = tid - DB;
        float xv = x[row * 3 + ci] + fin[1 + ci];
        out[H_ELEMS + row * 3 + ci] = xv;
    }
}

extern "C" void kernel_launch(void* const* d_in, const int* in_sizes, int n_in,
                              void* d_out, int out_size, void* d_ws, size_t ws_size,
                              hipStream_t stream) {
    const float* h    = (const float*)d_in[0];
    const float* x    = (const float*)d_in[1];
    const float* rij  = (const float*)d_in[2];
    const float* dij  = (const float*)d_in[3];
    const float* mask = (const float*)d_in[4];
    const float* eW1  = (const float*)d_in[5];
    const float* eb1  = (const float*)d_in[6];
    const float* eW2  = (const float*)d_in[7];
    const float* eb2  = (const float*)d_in[8];
    const float* eW3  = (const float*)d_in[9];
    const float* eb3  = (const float*)d_in[10];
    const float* pW1  = (const float*)d_in[11];
    const float* pb1  = (const float*)d_in[12];
    const float* pW2  = (const float*)d_in[13];
    const float* pb2  = (const float*)d_in[14];
    const float* nW1  = (const float*)d_in[15];
    const float* nb1  = (const float*)d_in[16];
    const float* nW2  = (const float*)d_in[17];
    const float* nb2  = (const float*)d_in[18];
    const float* Wih  = (const float*)d_in[19];
    const float* bih  = (const float*)d_in[20];
    const float* Whh  = (const float*)d_in[21];
    const float* bhh  = (const float*)d_in[22];

    float* A = (float*)d_ws;            // 2048
    float* C = A + ROWS;                // 2048
    float* U = C + ROWS;                // 192
    float* V = U + 3 * DB;              // 192

    egnn_pre<<<(ROWS + 3 * DB + 255) / 256, 256, 0, stream>>>(
        h, eW1, nW2, nb2, Wih, bih, A, C, U, V);

    egnn_main<<<ROWS, 256, 0, stream>>>(
        h, x, rij, dij, mask,
        eW1, eb1, eW2, eb2, eW3, eb3,
        pW1, pb1, pW2, pb2, nW1, nb1,
        Whh, bhh, A, C, U, V,
        (float*)d_out);
}